// Round 2
// baseline (2585.756 us; speedup 1.0000x reference)
//
#include <hip/hip_runtime.h>
#include <hip/hip_bf16.h>
#include <hip/hip_cooperative_groups.h>

namespace cg = cooperative_groups;

typedef unsigned short ushort_t;
typedef unsigned int uint_t;
typedef short bf8 __attribute__((ext_vector_type(8)));
typedef float f4 __attribute__((ext_vector_type(4)));

#define PDIM 2048
#define BDIM 8192
#define LM2 48          // Lanczos iterations (cooperative path)
#define LMF 64          // Lanczos iterations (fallback path)

// ---------------- helpers ----------------
__device__ __forceinline__ unsigned short f2bf(float x) {
    unsigned u = __float_as_uint(x);
    unsigned r = (u + 0x7fffu + ((u >> 16) & 1u)) >> 16;   // RTNE
    return (unsigned short)r;
}
__device__ __forceinline__ float bf2f(unsigned short h) {
    return __uint_as_float(((unsigned)h) << 16);
}
__device__ __forceinline__ void gload16(const void* g, void* l) {
    __builtin_amdgcn_global_load_lds(
        (const __attribute__((address_space(1))) unsigned int*)g,
        (__attribute__((address_space(3))) unsigned int*)l, 16, 0, 0);
}
__device__ __forceinline__ float hash_to_float(unsigned x) {
    x = (x ^ 61u) ^ (x >> 16);
    x *= 9u;
    x ^= x >> 4;
    x *= 0x27d4eb2du;
    x ^= x >> 15;
    return (float)(x & 0xFFFFFFu) / 16777216.0f - 0.5f;
}
__device__ __forceinline__ float block_reduce_bcast(float v, float* red) {
#pragma unroll
    for (int o = 32; o; o >>= 1) v += __shfl_xor(v, o, 64);
    const int w = threadIdx.x >> 6;
    __syncthreads();
    if ((threadIdx.x & 63) == 0) red[w] = v;
    __syncthreads();
    return red[0] + red[1] + red[2] + red[3];
}

// ---------------- prepass: transpose + hi/lo split ----------------
// G (8192 k x 2048 i) fp32 -> Ht, Lt (2048 i x 8192 k) bf16.
__global__ __launch_bounds__(256) void split_transpose(const float* __restrict__ G,
                                                       ushort_t* __restrict__ Ht,
                                                       ushort_t* __restrict__ Lt) {
    __shared__ float tile[64][65];
    const int k0 = blockIdx.x * 64;   // 128 blocks along k
    const int i0 = blockIdx.y * 64;   // 32 blocks along i
    const int t = threadIdx.x;
    {
        const int r = t >> 4;              // 0..15
        const int c4 = (t & 15) << 2;      // 0..60
#pragma unroll
        for (int p = 0; p < 4; ++p) {
            const int row = p * 16 + r;
            float4 v = *(const float4*)&G[(size_t)(k0 + row) * PDIM + i0 + c4];
            tile[row][c4 + 0] = v.x; tile[row][c4 + 1] = v.y;
            tile[row][c4 + 2] = v.z; tile[row][c4 + 3] = v.w;
        }
    }
    __syncthreads();
    {
        const int kc = (t & 7) * 8;        // 0..56
        const int il = t >> 3;             // 0..31
#pragma unroll
        for (int p = 0; p < 2; ++p) {
            const int i = p * 32 + il;
            uint_t hw[4], lw[4];
#pragma unroll
            for (int e = 0; e < 4; ++e) {
                float v0 = tile[kc + 2 * e][i];
                float v1 = tile[kc + 2 * e + 1][i];
                unsigned short h0 = f2bf(v0), h1 = f2bf(v1);
                unsigned short l0 = f2bf(v0 - bf2f(h0)), l1 = f2bf(v1 - bf2f(h1));
                hw[e] = (uint_t)h0 | ((uint_t)h1 << 16);
                lw[e] = (uint_t)l0 | ((uint_t)l1 << 16);
            }
            const size_t ofs = (size_t)(i0 + i) * BDIM + k0 + kc;
            *(uint4*)&Ht[ofs] = make_uint4(hw[0], hw[1], hw[2], hw[3]);
            *(uint4*)&Lt[ofs] = make_uint4(lw[0], lw[1], lw[2], lw[3]);
        }
    }
}

// ---------------- MFMA GEMM: lower-triangle tiles of F ----------------
// 128x128 tile, BK=64, 512 threads (8 waves as 2M x 4N), split-bf16 (hh+hl+lh).
#define GBK 64
__global__ __launch_bounds__(512) void fisher_gemm_mfma(const ushort_t* __restrict__ Ht,
                                                        const ushort_t* __restrict__ Lt,
                                                        float* __restrict__ F) {
    __shared__ ushort_t lds_all[4 * 128 * GBK];   // As_h | As_l | Bs_h | Bs_l (64 KB)
    // triangular decode: bi >= bj
    int tb = blockIdx.x;
    int bi = (int)((sqrtf(8.0f * (float)tb + 1.0f) - 1.0f) * 0.5f);
    while ((bi * (bi + 1)) / 2 > tb) --bi;
    while (((bi + 1) * (bi + 2)) / 2 <= tb) ++bi;
    const int bj = tb - (bi * (bi + 1)) / 2;
    const int i0 = bi * 128, j0 = bj * 128;

    const int tid = threadIdx.x;
    const int wave = tid >> 6, lane = tid & 63;
    const int wm = wave >> 2, wn = wave & 3;      // 2 x 4 waves
    const int lq = lane >> 4;                     // k-quarter 0..3
    const int lr = lane & 15;                     // spatial index

    f4 acc[4][2] = {};

    for (int k0 = 0; k0 < BDIM; k0 += GBK) {
        __syncthreads();   // previous compute done before overwrite
        // stage 4 tiles of [128][64] bf16; chunk = 16B (8 elems); 8 chunks/row.
        // LDS slot (row,c) <- global chunk (row, c ^ (row&7))  [pre-swizzled source]
#pragma unroll
        for (int half = 0; half < 2; ++half) {
            const int s = half * 512 + tid;       // 0..1023
            const int row = s >> 3, c = s & 7;
            const int csrc = c ^ (row & 7);
            const size_t goA = (size_t)(i0 + row) * BDIM + k0 + csrc * 8;
            const size_t goB = (size_t)(j0 + row) * BDIM + k0 + csrc * 8;
            gload16(Ht + goA, lds_all + 0 * 8192 + s * 8);
            gload16(Lt + goA, lds_all + 1 * 8192 + s * 8);
            gload16(Ht + goB, lds_all + 2 * 8192 + s * 8);
            gload16(Lt + goB, lds_all + 3 * 8192 + s * 8);
        }
        __syncthreads();   // barrier drains vmcnt -> LDS ready
#pragma unroll
        for (int ks = 0; ks < 2; ++ks) {          // two K=32 sub-steps
            const int cgk = ks * 4 + lq;          // global chunk 0..7
            bf8 ah[4], alx[4], bh[2], blx[2];
#pragma unroll
            for (int m = 0; m < 4; ++m) {
                const int row = wm * 64 + m * 16 + lr;
                const int cc = cgk ^ (row & 7);
                const ushort_t* p = lds_all + row * GBK + cc * 8;
                ah[m]  = *(const bf8*)p;
                alx[m] = *(const bf8*)(p + 8192);
            }
#pragma unroll
            for (int n = 0; n < 2; ++n) {
                const int row = wn * 32 + n * 16 + lr;
                const int cc = cgk ^ (row & 7);
                const ushort_t* p = lds_all + 2 * 8192 + row * GBK + cc * 8;
                bh[n]  = *(const bf8*)p;
                blx[n] = *(const bf8*)(p + 8192);
            }
#pragma unroll
            for (int m = 0; m < 4; ++m)
#pragma unroll
                for (int n = 0; n < 2; ++n) {
                    acc[m][n] = __builtin_amdgcn_mfma_f32_16x16x32_bf16(ah[m],  bh[n],  acc[m][n], 0, 0, 0);
                    acc[m][n] = __builtin_amdgcn_mfma_f32_16x16x32_bf16(ah[m],  blx[n], acc[m][n], 0, 0, 0);
                    acc[m][n] = __builtin_amdgcn_mfma_f32_16x16x32_bf16(alx[m], bh[n],  acc[m][n], 0, 0, 0);
                }
        }
    }
    const float scale = 1.0f / (float)BDIM;
#pragma unroll
    for (int m = 0; m < 4; ++m)
#pragma unroll
        for (int n = 0; n < 2; ++n) {
            const int row0 = i0 + wm * 64 + m * 16 + lq * 4;
            const int col  = j0 + wn * 32 + n * 16 + lr;
#pragma unroll
            for (int r = 0; r < 4; ++r)
                F[(size_t)(row0 + r) * PDIM + col] = acc[m][n][r] * scale;
        }
}

// ---------------- mirror: fill strict upper tiles ----------------
__global__ __launch_bounds__(256) void mirror_upper(float* __restrict__ F) {
    int tb = blockIdx.x;                       // 120 blocks: pairs a>b
    int a = (int)((1.0f + sqrtf(1.0f + 8.0f * (float)tb)) * 0.5f);
    while ((a * (a - 1)) / 2 > tb) --a;
    while (((a + 1) * a) / 2 <= tb) ++a;
    const int b = tb - (a * (a - 1)) / 2;      // dest tile (b, a), src tile (a, b)
    __shared__ float tile[32][33];
    const int t = threadIdx.x;
    const int lr = t >> 3;                     // 0..31
    const int lc = (t & 7) * 4;                // 0..28
    for (int rc = 0; rc < 4; ++rc)
        for (int cc = 0; cc < 4; ++cc) {
            float4 v = *(const float4*)&F[(size_t)(a * 128 + cc * 32 + lr) * PDIM + b * 128 + rc * 32 + lc];
            tile[lr][lc + 0] = v.x; tile[lr][lc + 1] = v.y;
            tile[lr][lc + 2] = v.z; tile[lr][lc + 3] = v.w;
            __syncthreads();
            float4 o;
            o.x = tile[lc + 0][lr]; o.y = tile[lc + 1][lr];
            o.z = tile[lc + 2][lr]; o.w = tile[lc + 3][lr];
            *(float4*)&F[(size_t)(b * 128 + rc * 32 + lr) * PDIM + a * 128 + cc * 32 + lc] = o;
            __syncthreads();
        }
}

// ---------------- cooperative Lanczos ----------------
__global__ __launch_bounds__(256) void lanczos_coop(const float* __restrict__ F,
                                                    float* __restrict__ tbuf,
                                                    float* __restrict__ out) {
    cg::grid_group grid = cg::this_grid();
    __shared__ __align__(16) float ua[PDIM];
    __shared__ __align__(16) float ub[PDIM];
    __shared__ float red[4];
    __shared__ float al[LM2], be[LM2 + 1];
    const int tid = threadIdx.x;
    const int wave = tid >> 6, lane = tid & 63;
    const int bid = blockIdx.x;

    float ss = 0.f;
    for (int i = tid; i < PDIM; i += 256) {
        float v = hash_to_float((unsigned)i * 2654435761u + 12345u);
        ua[i] = v; ub[i] = 0.f; ss += v * v;
    }
    ss = block_reduce_bcast(ss, red);
    const float inv0 = 1.0f / sqrtf(ss);
    for (int i = tid; i < PDIM; i += 256) ua[i] *= inv0;
    __syncthreads();

    float* vj = ua;
    float* vm = ub;
    float beta = 0.f;
    for (int j = 0; j < LM2; ++j) {
        float* tj = tbuf + (j & 1) * PDIM;
        // phase A: this block's 8 rows of t = F v
#pragma unroll
        for (int p = 0; p < 2; ++p) {
            const int row = bid * 8 + wave * 2 + p;
            const float4* Fr = (const float4*)(F + (size_t)row * PDIM);
            const float4* uv = (const float4*)vj;
            float s = 0.f;
#pragma unroll
            for (int c = 0; c < 8; ++c) {
                float4 f = Fr[c * 64 + lane];
                float4 u = uv[c * 64 + lane];
                s += f.x * u.x + f.y * u.y + f.z * u.z + f.w * u.w;
            }
#pragma unroll
            for (int o = 32; o; o >>= 1) s += __shfl_xor(s, o, 64);
            if (lane == 0) tj[row] = s;
        }
        __threadfence();
        grid.sync();
        // phase B: redundant per-block update (bitwise identical everywhere)
        float tl[8];
        float d = 0.f;
#pragma unroll
        for (int e = 0; e < 8; ++e) {
            const int i = e * 256 + tid;
            tl[e] = tj[i];
            d += tl[e] * vj[i];
        }
        d = block_reduce_bcast(d, red);
        float sq = 0.f;
        float wl[8];
#pragma unroll
        for (int e = 0; e < 8; ++e) {
            const int i = e * 256 + tid;
            const float w = tl[e] - d * vj[i] - beta * vm[i];
            wl[e] = w; sq += w * w;
        }
        sq = block_reduce_bcast(sq, red);
        const float bnew = sqrtf(fmaxf(sq, 1e-30f));
        const float invb = 1.0f / bnew;
#pragma unroll
        for (int e = 0; e < 8; ++e) {
            const int i = e * 256 + tid;
            vm[i] = wl[e] * invb;
        }
        if (tid == 0) { al[j] = d; be[j + 1] = bnew; }
        __syncthreads();
        float* tmp = vj; vj = vm; vm = tmp;
        beta = bnew;
    }
    // final: Sturm multisection, block 0 / wave 0
    if (bid == 0 && wave == 0) {
        float lo = 1e30f, hi = 1e30f;
        for (int j = 0; j < LM2; ++j) {
            const float bl2 = (j > 0) ? be[j] : 0.f;
            const float br = (j < LM2 - 1) ? be[j + 1] : 0.f;
            lo = fminf(lo, al[j] - bl2 - br);
            hi = fminf(hi, al[j]);
        }
        lo -= 1e-4f; hi += 1e-4f;
        for (int round = 0; round < 4; ++round) {
            const float x = lo + (hi - lo) * (float)(lane + 1) * (1.0f / 65.0f);
            int cnt = 0;
            float q = 1.f;
            for (int j = 0; j < LM2; ++j) {
                const float b2 = (j > 0) ? be[j] * be[j] : 0.f;
                q = al[j] - x - b2 / q;
                if (q < 0.f) cnt++;
                if (fabsf(q) < 1e-20f) q = -1e-20f;
            }
            unsigned long long msk = __ballot(cnt >= 1);
            const int fb = (msk == 0ull) ? 64 : (__ffsll((unsigned long long)msk) - 1);
            const float w = (hi - lo) * (1.0f / 65.0f);
            const float nlo = lo + w * (float)fb;
            const float nhi = (fb < 64) ? lo + w * (float)(fb + 1) : hi;
            lo = nlo; hi = nhi;
        }
        if (lane == 0) {
            const float lam = 0.5f * (lo + hi);
            out[0] = 0.1f * fmaxf(0.f, 1.f - lam);
        }
    }
}

// ================= fallback path (round-1, known-good) =================
#define BM 64
#define BN 64
#define BK 16
__global__ __launch_bounds__(256) void fisher_gemm_fb(const float* __restrict__ G,
                                                      float* __restrict__ F) {
    __shared__ float As[BK][BM];
    __shared__ float Bs[BK][BN];
    const int i0 = blockIdx.y * BM;
    const int j0 = blockIdx.x * BN;
    const int tid = threadIdx.x;
    const int tr = tid >> 4;
    const int tc = tid & 15;
    const int lrow = tid >> 4;
    const int lcol = (tid & 15) * 4;
    float acc[4][4] = {};
    for (int k0 = 0; k0 < BDIM; k0 += BK) {
        const float* gA = G + (size_t)(k0 + lrow) * PDIM + i0 + lcol;
        const float* gB = G + (size_t)(k0 + lrow) * PDIM + j0 + lcol;
        float4 a4 = *(const float4*)gA;
        float4 b4 = *(const float4*)gB;
        __syncthreads();
        *(float4*)&As[lrow][lcol] = a4;
        *(float4*)&Bs[lrow][lcol] = b4;
        __syncthreads();
#pragma unroll
        for (int kk = 0; kk < BK; ++kk) {
            float4 av = *(const float4*)&As[kk][tr * 4];
            float4 bv = *(const float4*)&Bs[kk][tc * 4];
            float a[4] = {av.x, av.y, av.z, av.w};
            float b[4] = {bv.x, bv.y, bv.z, bv.w};
#pragma unroll
            for (int x = 0; x < 4; ++x)
#pragma unroll
                for (int y = 0; y < 4; ++y) acc[x][y] += a[x] * b[y];
        }
    }
    const float scale = 1.0f / (float)BDIM;
#pragma unroll
    for (int x = 0; x < 4; ++x)
#pragma unroll
        for (int y = 0; y < 4; ++y)
            F[(size_t)(i0 + tr * 4 + x) * PDIM + (j0 + tc * 4 + y)] = acc[x][y] * scale;
}

__global__ void lanczos_init_fb(float* __restrict__ uA, float* __restrict__ uB,
                                float* __restrict__ S, float* __restrict__ D) {
    const int tid = threadIdx.x;
    if (tid < LMF + 2) S[tid] = (tid == 0) ? 1.0f : 0.0f;
    if (tid < LMF) D[tid] = 0.0f;
    float local = 0.0f;
    for (int i = tid; i < PDIM; i += 256) {
        uB[i] = 0.0f;
        float v = hash_to_float((unsigned)i * 2654435761u + 12345u);
        uA[i] = v;
        local += v * v;
    }
    for (int off = 32; off; off >>= 1) local += __shfl_down(local, off, 64);
    __shared__ float red[4];
    if ((tid & 63) == 0) red[tid >> 6] = local;
    __syncthreads();
    if (tid == 0) S[1] = red[0] + red[1] + red[2] + red[3];
}

__global__ __launch_bounds__(256) void lanczos_mv_fb(const float* __restrict__ F,
                                                     const float* __restrict__ u,
                                                     float* __restrict__ t,
                                                     float* d_accum) {
    const int row = blockIdx.x * 4 + (threadIdx.x >> 6);
    const int lane = threadIdx.x & 63;
    const float* Frow = F + (size_t)row * PDIM;
    float sum = 0.0f;
    for (int c = lane * 4; c < PDIM; c += 256) {
        float4 f4 = *(const float4*)&Frow[c];
        float4 u4 = *(const float4*)&u[c];
        sum += f4.x * u4.x + f4.y * u4.y + f4.z * u4.z + f4.w * u4.w;
    }
    for (int off = 32; off; off >>= 1) sum += __shfl_down(sum, off, 64);
    __shared__ float red[4];
    if (lane == 0) {
        t[row] = sum;
        red[threadIdx.x >> 6] = sum * u[row];
    }
    __syncthreads();
    if (threadIdx.x == 0) atomicAdd(d_accum, red[0] + red[1] + red[2] + red[3]);
}

__global__ void lanczos_upd_fb(const float* __restrict__ t, const float* __restrict__ u,
                               float* __restrict__ upn,
                               const float* pSj, const float* pSjm1,
                               const float* pDj, float* pSjp1) {
    const float s_j = *pSj;
    const float s_jm1 = *pSjm1;
    const float d_j = *pDj;
    const float n_j = sqrtf(s_j);
    const float inv_n = 1.0f / n_j;
    const float alpha = d_j / s_j;
    const float c_u = alpha * inv_n;
    const float c_p = n_j / sqrtf(s_jm1);
    const int i = blockIdx.x * blockDim.x + threadIdx.x;
    const float un = t[i] * inv_n - c_u * u[i] - c_p * upn[i];
    upn[i] = un;
    float sq = un * un;
    for (int off = 32; off; off >>= 1) sq += __shfl_down(sq, off, 64);
    __shared__ float red[4];
    if ((threadIdx.x & 63) == 0) red[threadIdx.x >> 6] = sq;
    __syncthreads();
    if (threadIdx.x == 0) atomicAdd(pSjp1, red[0] + red[1] + red[2] + red[3]);
}

__global__ void lanczos_final_fb(const float* __restrict__ S, const float* __restrict__ D,
                                 float* __restrict__ out) {
    double diag[LMF], off[LMF - 1];
    for (int j = 0; j < LMF; ++j) diag[j] = (double)D[j] / (double)S[j + 1];
    for (int j = 0; j < LMF - 1; ++j) off[j] = sqrt((double)S[j + 2]);
    double lo = 1e300, hi = 1e300;
    for (int j = 0; j < LMF; ++j) {
        double r = diag[j];
        if (j > 0) r -= fabs(off[j - 1]);
        if (j < LMF - 1) r -= fabs(off[j]);
        lo = fmin(lo, r);
        hi = fmin(hi, diag[j]);
    }
    lo -= 1e-3; hi += 1e-3;
    for (int it = 0; it < 60 && (hi - lo) > 1e-10; ++it) {
        double x = 0.5 * (lo + hi);
        int cnt = 0;
        double q = 1.0;
        for (int j = 0; j < LMF; ++j) {
            double b2 = (j > 0) ? off[j - 1] * off[j - 1] : 0.0;
            q = diag[j] - x - b2 / q;
            if (q < 0.0) cnt++;
            if (fabs(q) < 1e-300) q = -1e-300;
        }
        if (cnt >= 1) hi = x; else lo = x;
    }
    double lam = 0.5 * (lo + hi);
    double pen = 1.0 - lam;
    if (pen < 0.0) pen = 0.0;
    out[0] = (float)(0.1 * pen);
}

// ---------------- launch ----------------
extern "C" void kernel_launch(void* const* d_in, const int* in_sizes, int n_in,
                              void* d_out, int out_size, void* d_ws, size_t ws_size,
                              hipStream_t stream) {
    const float* G = (const float*)d_in[0];
    char* ws = (char*)d_ws;

    const size_t F_OFF  = 0;
    const size_t HT_OFF = 16777216;            // 16.8 MB
    const size_t LT_OFF = HT_OFF + 33554432;   // +33.6 MB
    const size_t TB_OFF = LT_OFF + 33554432;
    const size_t NEED   = TB_OFF + 2 * PDIM * sizeof(float);

    if (ws_size >= NEED) {
        float*    F  = (float*)(ws + F_OFF);
        ushort_t* Ht = (ushort_t*)(ws + HT_OFF);
        ushort_t* Lt = (ushort_t*)(ws + LT_OFF);
        float*    tb = (float*)(ws + TB_OFF);
        float*    outp = (float*)d_out;

        split_transpose<<<dim3(BDIM / 64, PDIM / 64), 256, 0, stream>>>(G, Ht, Lt);
        fisher_gemm_mfma<<<136, 512, 0, stream>>>(Ht, Lt, F);
        mirror_upper<<<120, 256, 0, stream>>>(F);

        void* kargs[3] = {(void*)&F, (void*)&tb, (void*)&outp};
        hipLaunchCooperativeKernel((const void*)lanczos_coop, dim3(256), dim3(256),
                                   kargs, 0, stream);
    } else {
        // fallback: round-1 path (needs only ~16.9 MB of ws)
        float* F  = (float*)d_ws;
        float* uA = F + (size_t)PDIM * PDIM;
        float* uB = uA + PDIM;
        float* t  = uB + PDIM;
        float* S  = t + PDIM;
        float* D  = S + (LMF + 2);

        fisher_gemm_fb<<<dim3(PDIM / BN, PDIM / BM), 256, 0, stream>>>(G, F);
        lanczos_init_fb<<<1, 256, 0, stream>>>(uA, uB, S, D);
        float* uc = uA;
        float* up = uB;
        for (int j = 0; j < LMF; ++j) {
            lanczos_mv_fb<<<PDIM / 4, 256, 0, stream>>>(F, uc, t, &D[j]);
            lanczos_upd_fb<<<PDIM / 256, 256, 0, stream>>>(t, uc, up, &S[j + 1], &S[j], &D[j], &S[j + 2]);
            float* tmp = up; up = uc; uc = tmp;
        }
        lanczos_final_fb<<<1, 1, 0, stream>>>(S, D, (float*)d_out);
    }
}

// Round 3
// 655.047 us; speedup vs baseline: 3.9474x; 3.9474x over previous
//
#include <hip/hip_runtime.h>
#include <hip/hip_bf16.h>

typedef unsigned short ushort_t;
typedef unsigned int uint_t;
typedef short bf8 __attribute__((ext_vector_type(8)));
typedef float f4 __attribute__((ext_vector_type(4)));

#define PDIM 2048
#define BDIM 8192
#define LM2 48          // Lanczos iterations (main path)
#define LMF 64          // Lanczos iterations (fallback path)
#define NB  256         // blocks in lanczos_step

// ---------------- helpers ----------------
__device__ __forceinline__ unsigned short f2bf(float x) {
    unsigned u = __float_as_uint(x);
    unsigned r = (u + 0x7fffu + ((u >> 16) & 1u)) >> 16;   // RTNE
    return (unsigned short)r;
}
__device__ __forceinline__ float bf2f(unsigned short h) {
    return __uint_as_float(((unsigned)h) << 16);
}
__device__ __forceinline__ void gload16(const void* g, void* l) {
    __builtin_amdgcn_global_load_lds(
        (const __attribute__((address_space(1))) unsigned int*)g,
        (__attribute__((address_space(3))) unsigned int*)l, 16, 0, 0);
}
__device__ __forceinline__ float hash_to_float(unsigned x) {
    x = (x ^ 61u) ^ (x >> 16);
    x *= 9u;
    x ^= x >> 4;
    x *= 0x27d4eb2du;
    x ^= x >> 15;
    return (float)(x & 0xFFFFFFu) / 16777216.0f - 0.5f;
}
__device__ __forceinline__ float block_reduce_bcast(float v, float* red) {
#pragma unroll
    for (int o = 32; o; o >>= 1) v += __shfl_xor(v, o, 64);
    const int w = threadIdx.x >> 6;
    __syncthreads();
    if ((threadIdx.x & 63) == 0) red[w] = v;
    __syncthreads();
    return red[0] + red[1] + red[2] + red[3];
}

// ---------------- prepass: transpose + hi/lo split ----------------
// G (8192 k x 2048 i) fp32 -> Ht, Lt (2048 i x 8192 k) bf16.
__global__ __launch_bounds__(256) void split_transpose(const float* __restrict__ G,
                                                       ushort_t* __restrict__ Ht,
                                                       ushort_t* __restrict__ Lt) {
    __shared__ float tile[64][65];
    const int k0 = blockIdx.x * 64;
    const int i0 = blockIdx.y * 64;
    const int t = threadIdx.x;
    {
        const int r = t >> 4;
        const int c4 = (t & 15) << 2;
#pragma unroll
        for (int p = 0; p < 4; ++p) {
            const int row = p * 16 + r;
            float4 v = *(const float4*)&G[(size_t)(k0 + row) * PDIM + i0 + c4];
            tile[row][c4 + 0] = v.x; tile[row][c4 + 1] = v.y;
            tile[row][c4 + 2] = v.z; tile[row][c4 + 3] = v.w;
        }
    }
    __syncthreads();
    {
        const int kc = (t & 7) * 8;
        const int il = t >> 3;
#pragma unroll
        for (int p = 0; p < 2; ++p) {
            const int i = p * 32 + il;
            uint_t hw[4], lw[4];
#pragma unroll
            for (int e = 0; e < 4; ++e) {
                float v0 = tile[kc + 2 * e][i];
                float v1 = tile[kc + 2 * e + 1][i];
                unsigned short h0 = f2bf(v0), h1 = f2bf(v1);
                unsigned short l0 = f2bf(v0 - bf2f(h0)), l1 = f2bf(v1 - bf2f(h1));
                hw[e] = (uint_t)h0 | ((uint_t)h1 << 16);
                lw[e] = (uint_t)l0 | ((uint_t)l1 << 16);
            }
            const size_t ofs = (size_t)(i0 + i) * BDIM + k0 + kc;
            *(uint4*)&Ht[ofs] = make_uint4(hw[0], hw[1], hw[2], hw[3]);
            *(uint4*)&Lt[ofs] = make_uint4(lw[0], lw[1], lw[2], lw[3]);
        }
    }
}

// ---------------- MFMA GEMM: lower-triangle tiles of F ----------------
#define GBK 64
__global__ __launch_bounds__(512) void fisher_gemm_mfma(const ushort_t* __restrict__ Ht,
                                                        const ushort_t* __restrict__ Lt,
                                                        float* __restrict__ F) {
    __shared__ ushort_t lds_all[4 * 128 * GBK];   // 64 KB
    int tb = blockIdx.x;
    int bi = (int)((sqrtf(8.0f * (float)tb + 1.0f) - 1.0f) * 0.5f);
    while ((bi * (bi + 1)) / 2 > tb) --bi;
    while (((bi + 1) * (bi + 2)) / 2 <= tb) ++bi;
    const int bj = tb - (bi * (bi + 1)) / 2;
    const int i0 = bi * 128, j0 = bj * 128;

    const int tid = threadIdx.x;
    const int wave = tid >> 6, lane = tid & 63;
    const int wm = wave >> 2, wn = wave & 3;
    const int lq = lane >> 4;
    const int lr = lane & 15;

    f4 acc[4][2] = {};

    for (int k0 = 0; k0 < BDIM; k0 += GBK) {
        __syncthreads();
#pragma unroll
        for (int half = 0; half < 2; ++half) {
            const int s = half * 512 + tid;
            const int row = s >> 3, c = s & 7;
            const int csrc = c ^ (row & 7);
            const size_t goA = (size_t)(i0 + row) * BDIM + k0 + csrc * 8;
            const size_t goB = (size_t)(j0 + row) * BDIM + k0 + csrc * 8;
            gload16(Ht + goA, lds_all + 0 * 8192 + s * 8);
            gload16(Lt + goA, lds_all + 1 * 8192 + s * 8);
            gload16(Ht + goB, lds_all + 2 * 8192 + s * 8);
            gload16(Lt + goB, lds_all + 3 * 8192 + s * 8);
        }
        __syncthreads();
#pragma unroll
        for (int ks = 0; ks < 2; ++ks) {
            const int cgk = ks * 4 + lq;
            bf8 ah[4], alx[4], bh[2], blx[2];
#pragma unroll
            for (int m = 0; m < 4; ++m) {
                const int row = wm * 64 + m * 16 + lr;
                const int cc = cgk ^ (row & 7);
                const ushort_t* p = lds_all + row * GBK + cc * 8;
                ah[m]  = *(const bf8*)p;
                alx[m] = *(const bf8*)(p + 8192);
            }
#pragma unroll
            for (int n = 0; n < 2; ++n) {
                const int row = wn * 32 + n * 16 + lr;
                const int cc = cgk ^ (row & 7);
                const ushort_t* p = lds_all + 2 * 8192 + row * GBK + cc * 8;
                bh[n]  = *(const bf8*)p;
                blx[n] = *(const bf8*)(p + 8192);
            }
#pragma unroll
            for (int m = 0; m < 4; ++m)
#pragma unroll
                for (int n = 0; n < 2; ++n) {
                    acc[m][n] = __builtin_amdgcn_mfma_f32_16x16x32_bf16(ah[m],  bh[n],  acc[m][n], 0, 0, 0);
                    acc[m][n] = __builtin_amdgcn_mfma_f32_16x16x32_bf16(ah[m],  blx[n], acc[m][n], 0, 0, 0);
                    acc[m][n] = __builtin_amdgcn_mfma_f32_16x16x32_bf16(alx[m], bh[n],  acc[m][n], 0, 0, 0);
                }
        }
    }
    const float scale = 1.0f / (float)BDIM;
#pragma unroll
    for (int m = 0; m < 4; ++m)
#pragma unroll
        for (int n = 0; n < 2; ++n) {
            const int row0 = i0 + wm * 64 + m * 16 + lq * 4;
            const int col  = j0 + wn * 32 + n * 16 + lr;
#pragma unroll
            for (int r = 0; r < 4; ++r)
                F[(size_t)(row0 + r) * PDIM + col] = acc[m][n][r] * scale;
        }
}

// ---------------- mirror: fill strict upper tiles ----------------
__global__ __launch_bounds__(256) void mirror_upper(float* __restrict__ F) {
    int tb = blockIdx.x;
    int a = (int)((1.0f + sqrtf(1.0f + 8.0f * (float)tb)) * 0.5f);
    while ((a * (a - 1)) / 2 > tb) --a;
    while (((a + 1) * a) / 2 <= tb) ++a;
    const int b = tb - (a * (a - 1)) / 2;
    __shared__ float tile[32][33];
    const int t = threadIdx.x;
    const int lr = t >> 3;
    const int lc = (t & 7) * 4;
    for (int rc = 0; rc < 4; ++rc)
        for (int cc = 0; cc < 4; ++cc) {
            float4 v = *(const float4*)&F[(size_t)(a * 128 + cc * 32 + lr) * PDIM + b * 128 + rc * 32 + lc];
            tile[lr][lc + 0] = v.x; tile[lr][lc + 1] = v.y;
            tile[lr][lc + 2] = v.z; tile[lr][lc + 3] = v.w;
            __syncthreads();
            float4 o;
            o.x = tile[lc + 0][lr]; o.y = tile[lc + 1][lr];
            o.z = tile[lc + 2][lr]; o.w = tile[lc + 3][lr];
            *(float4*)&F[(size_t)(b * 128 + rc * 32 + lr) * PDIM + a * 128 + cc * 32 + lc] = o;
            __syncthreads();
        }
}

// ---------------- pipelined Lanczos: one dispatch per iteration ----------------
// Dispatch j (j=0..LM2-1):
//  phase 1 (every block, redundant & bitwise identical):
//    j==0 : v0 = hash / ||hash||
//    j>=1 : alpha_{j-1} = sum(dpart[j-1][0..255]); w = t_{j-1} - alpha*v_{j-1}
//           - (j>=2 ? be[j-1]*v_{j-2} : 0); be[j]=||w||; v_j = w/be[j]
//  block 0 stores v_j to vbuf[j%3]; be[j] to global.
//  phase 2: block's 8 rows of t_j = F v_j -> tbuf[j&1]; dpart[j][bid] = partial v_j.t_j
__global__ __launch_bounds__(256) void lanczos_step(const float* __restrict__ F,
                                                    float* __restrict__ vbuf,
                                                    float* __restrict__ tbuf,
                                                    float* __restrict__ dpart,
                                                    float* __restrict__ be,
                                                    int j) {
    __shared__ __align__(16) float vcur[PDIM];
    __shared__ float red[4];
    const int tid = threadIdx.x, bid = blockIdx.x;
    const int wave = tid >> 6, lane = tid & 63;

    if (j == 0) {
        float loc[8];
        float ss = 0.f;
#pragma unroll
        for (int e = 0; e < 8; ++e) {
            const int i = e * 256 + tid;
            float v = hash_to_float((unsigned)i * 2654435761u + 12345u);
            loc[e] = v; ss += v * v;
        }
        ss = block_reduce_bcast(ss, red);
        const float inv = 1.0f / sqrtf(ss);
#pragma unroll
        for (int e = 0; e < 8; ++e) vcur[e * 256 + tid] = loc[e] * inv;
        if (bid == 0 && tid == 0) be[0] = 0.f;
    } else {
        const float* tp = tbuf + ((j - 1) & 1) * PDIM;
        const float* v1 = vbuf + ((j - 1) % 3) * PDIM;
        const float* v2 = vbuf + ((j + 1) % 3) * PDIM;   // (j-2) mod 3
        float ap = dpart[(j - 1) * NB + tid];
        ap = block_reduce_bcast(ap, red);
        const float bprev = (j >= 2) ? be[j - 1] : 0.f;
        float w[8];
        float ss = 0.f;
#pragma unroll
        for (int e = 0; e < 8; ++e) {
            const int i = e * 256 + tid;
            float wv = tp[i] - ap * v1[i];
            if (j >= 2) wv -= bprev * v2[i];
            w[e] = wv; ss += wv * wv;
        }
        ss = block_reduce_bcast(ss, red);
        const float bj = sqrtf(fmaxf(ss, 1e-30f));
        const float inv = 1.0f / bj;
#pragma unroll
        for (int e = 0; e < 8; ++e) vcur[e * 256 + tid] = w[e] * inv;
        if (bid == 0 && tid == 0) be[j] = bj;
    }
    __syncthreads();
    if (bid == 0) {
        float* vd = vbuf + (j % 3) * PDIM;
#pragma unroll
        for (int e = 0; e < 8; ++e) {
            const int i = e * 256 + tid;
            vd[i] = vcur[i];
        }
    }
    // phase 2: matvec rows
    float* tc = tbuf + (j & 1) * PDIM;
    float dp = 0.f;
#pragma unroll
    for (int p = 0; p < 2; ++p) {
        const int row = bid * 8 + wave * 2 + p;
        const float4* Fr = (const float4*)(F + (size_t)row * PDIM);
        const float4* uv = (const float4*)vcur;
        float s = 0.f;
#pragma unroll
        for (int c = 0; c < 8; ++c) {
            float4 f = Fr[c * 64 + lane];
            float4 u = uv[c * 64 + lane];
            s += f.x * u.x + f.y * u.y + f.z * u.z + f.w * u.w;
        }
#pragma unroll
        for (int o = 32; o; o >>= 1) s += __shfl_xor(s, o, 64);
        if (lane == 0) {
            tc[row] = s;
            dp += s * vcur[row];
        }
    }
    dp = block_reduce_bcast(dp, red);   // non-lane0 contribute 0
    if (tid == 0) dpart[j * NB + bid] = dp;
}

// ---------------- final: assemble tridiagonal, Sturm multisection ----------------
__global__ __launch_bounds__(256) void lanczos_final2(const float* __restrict__ dpart,
                                                      const float* __restrict__ beg,
                                                      float* __restrict__ out) {
    __shared__ float al[LM2], be[LM2];
    const int tid = threadIdx.x;
    const int wave = tid >> 6, lane = tid & 63;
    // alpha_j = sum of dpart[j][0..255]; wave w handles j = w*12..w*12+11
    for (int k = 0; k < LM2 / 4; ++k) {
        const int j = wave * (LM2 / 4) + k;
        float s = dpart[j * NB + lane] + dpart[j * NB + 64 + lane]
                + dpart[j * NB + 128 + lane] + dpart[j * NB + 192 + lane];
#pragma unroll
        for (int o = 32; o; o >>= 1) s += __shfl_xor(s, o, 64);
        if (lane == 0) al[j] = s;
    }
    if (tid < LM2) be[tid] = beg[tid];
    __syncthreads();
    if (wave == 0) {
        float lo = 1e30f, hi = 1e30f;
        for (int j = 0; j < LM2; ++j) {
            const float bl = (j > 0) ? be[j] : 0.f;
            const float br = (j < LM2 - 1) ? be[j + 1] : 0.f;
            lo = fminf(lo, al[j] - bl - br);
            hi = fminf(hi, al[j]);
        }
        lo -= 1e-4f; hi += 1e-4f;
        for (int round = 0; round < 4; ++round) {
            const float x = lo + (hi - lo) * (float)(lane + 1) * (1.0f / 65.0f);
            int cnt = 0;
            float q = 1.f;
            for (int j = 0; j < LM2; ++j) {
                const float b2 = (j > 0) ? be[j] * be[j] : 0.f;
                q = al[j] - x - b2 / q;
                if (q < 0.f) cnt++;
                if (fabsf(q) < 1e-20f) q = -1e-20f;
            }
            unsigned long long msk = __ballot(cnt >= 1);
            const int fb = (msk == 0ull) ? 64 : (__ffsll((unsigned long long)msk) - 1);
            const float w = (hi - lo) * (1.0f / 65.0f);
            const float nlo = lo + w * (float)fb;
            const float nhi = (fb < 64) ? lo + w * (float)(fb + 1) : hi;
            lo = nlo; hi = nhi;
        }
        if (lane == 0) {
            const float lam = 0.5f * (lo + hi);
            out[0] = 0.1f * fmaxf(0.f, 1.f - lam);
        }
    }
}

// ================= fallback path (round-1, known-good) =================
#define BM 64
#define BN 64
#define BK 16
__global__ __launch_bounds__(256) void fisher_gemm_fb(const float* __restrict__ G,
                                                      float* __restrict__ F) {
    __shared__ float As[BK][BM];
    __shared__ float Bs[BK][BN];
    const int i0 = blockIdx.y * BM;
    const int j0 = blockIdx.x * BN;
    const int tid = threadIdx.x;
    const int tr = tid >> 4;
    const int tc = tid & 15;
    const int lrow = tid >> 4;
    const int lcol = (tid & 15) * 4;
    float acc[4][4] = {};
    for (int k0 = 0; k0 < BDIM; k0 += BK) {
        const float* gA = G + (size_t)(k0 + lrow) * PDIM + i0 + lcol;
        const float* gB = G + (size_t)(k0 + lrow) * PDIM + j0 + lcol;
        float4 a4 = *(const float4*)gA;
        float4 b4 = *(const float4*)gB;
        __syncthreads();
        *(float4*)&As[lrow][lcol] = a4;
        *(float4*)&Bs[lrow][lcol] = b4;
        __syncthreads();
#pragma unroll
        for (int kk = 0; kk < BK; ++kk) {
            float4 av = *(const float4*)&As[kk][tr * 4];
            float4 bv = *(const float4*)&Bs[kk][tc * 4];
            float a[4] = {av.x, av.y, av.z, av.w};
            float b[4] = {bv.x, bv.y, bv.z, bv.w};
#pragma unroll
            for (int x = 0; x < 4; ++x)
#pragma unroll
                for (int y = 0; y < 4; ++y) acc[x][y] += a[x] * b[y];
        }
    }
    const float scale = 1.0f / (float)BDIM;
#pragma unroll
    for (int x = 0; x < 4; ++x)
#pragma unroll
        for (int y = 0; y < 4; ++y)
            F[(size_t)(i0 + tr * 4 + x) * PDIM + (j0 + tc * 4 + y)] = acc[x][y] * scale;
}

__global__ void lanczos_init_fb(float* __restrict__ uA, float* __restrict__ uB,
                                float* __restrict__ S, float* __restrict__ D) {
    const int tid = threadIdx.x;
    if (tid < LMF + 2) S[tid] = (tid == 0) ? 1.0f : 0.0f;
    if (tid < LMF) D[tid] = 0.0f;
    float local = 0.0f;
    for (int i = tid; i < PDIM; i += 256) {
        uB[i] = 0.0f;
        float v = hash_to_float((unsigned)i * 2654435761u + 12345u);
        uA[i] = v;
        local += v * v;
    }
    for (int off = 32; off; off >>= 1) local += __shfl_down(local, off, 64);
    __shared__ float red[4];
    if ((tid & 63) == 0) red[tid >> 6] = local;
    __syncthreads();
    if (tid == 0) S[1] = red[0] + red[1] + red[2] + red[3];
}

__global__ __launch_bounds__(256) void lanczos_mv_fb(const float* __restrict__ F,
                                                     const float* __restrict__ u,
                                                     float* __restrict__ t,
                                                     float* d_accum) {
    const int row = blockIdx.x * 4 + (threadIdx.x >> 6);
    const int lane = threadIdx.x & 63;
    const float* Frow = F + (size_t)row * PDIM;
    float sum = 0.0f;
    for (int c = lane * 4; c < PDIM; c += 256) {
        float4 f4 = *(const float4*)&Frow[c];
        float4 u4 = *(const float4*)&u[c];
        sum += f4.x * u4.x + f4.y * u4.y + f4.z * u4.z + f4.w * u4.w;
    }
    for (int off = 32; off; off >>= 1) sum += __shfl_down(sum, off, 64);
    __shared__ float red[4];
    if (lane == 0) {
        t[row] = sum;
        red[threadIdx.x >> 6] = sum * u[row];
    }
    __syncthreads();
    if (threadIdx.x == 0) atomicAdd(d_accum, red[0] + red[1] + red[2] + red[3]);
}

__global__ void lanczos_upd_fb(const float* __restrict__ t, const float* __restrict__ u,
                               float* __restrict__ upn,
                               const float* pSj, const float* pSjm1,
                               const float* pDj, float* pSjp1) {
    const float s_j = *pSj;
    const float s_jm1 = *pSjm1;
    const float d_j = *pDj;
    const float n_j = sqrtf(s_j);
    const float inv_n = 1.0f / n_j;
    const float alpha = d_j / s_j;
    const float c_u = alpha * inv_n;
    const float c_p = n_j / sqrtf(s_jm1);
    const int i = blockIdx.x * blockDim.x + threadIdx.x;
    const float un = t[i] * inv_n - c_u * u[i] - c_p * upn[i];
    upn[i] = un;
    float sq = un * un;
    for (int off = 32; off; off >>= 1) sq += __shfl_down(sq, off, 64);
    __shared__ float red[4];
    if ((threadIdx.x & 63) == 0) red[threadIdx.x >> 6] = sq;
    __syncthreads();
    if (threadIdx.x == 0) atomicAdd(pSjp1, red[0] + red[1] + red[2] + red[3]);
}

__global__ void lanczos_final_fb(const float* __restrict__ S, const float* __restrict__ D,
                                 float* __restrict__ out) {
    double diag[LMF], off[LMF - 1];
    for (int j = 0; j < LMF; ++j) diag[j] = (double)D[j] / (double)S[j + 1];
    for (int j = 0; j < LMF - 1; ++j) off[j] = sqrt((double)S[j + 2]);
    double lo = 1e300, hi = 1e300;
    for (int j = 0; j < LMF; ++j) {
        double r = diag[j];
        if (j > 0) r -= fabs(off[j - 1]);
        if (j < LMF - 1) r -= fabs(off[j]);
        lo = fmin(lo, r);
        hi = fmin(hi, diag[j]);
    }
    lo -= 1e-3; hi += 1e-3;
    for (int it = 0; it < 60 && (hi - lo) > 1e-10; ++it) {
        double x = 0.5 * (lo + hi);
        int cnt = 0;
        double q = 1.0;
        for (int j = 0; j < LMF; ++j) {
            double b2 = (j > 0) ? off[j - 1] * off[j - 1] : 0.0;
            q = diag[j] - x - b2 / q;
            if (q < 0.0) cnt++;
            if (fabs(q) < 1e-300) q = -1e-300;
        }
        if (cnt >= 1) hi = x; else lo = x;
    }
    double lam = 0.5 * (lo + hi);
    double pen = 1.0 - lam;
    if (pen < 0.0) pen = 0.0;
    out[0] = (float)(0.1 * pen);
}

// ---------------- launch ----------------
extern "C" void kernel_launch(void* const* d_in, const int* in_sizes, int n_in,
                              void* d_out, int out_size, void* d_ws, size_t ws_size,
                              hipStream_t stream) {
    const float* G = (const float*)d_in[0];
    char* ws = (char*)d_ws;

    const size_t F_OFF  = 0;
    const size_t HT_OFF = 16777216;                       // F: 16.8 MB
    const size_t LT_OFF = HT_OFF + 33554432;              // Ht: 33.6 MB
    const size_t TB_OFF = LT_OFF + 33554432;              // Lt: 33.6 MB
    const size_t VB_OFF = TB_OFF + 2 * PDIM * sizeof(float);
    const size_t DP_OFF = VB_OFF + 3 * PDIM * sizeof(float);
    const size_t BE_OFF = DP_OFF + (size_t)LM2 * NB * sizeof(float);
    const size_t NEED   = BE_OFF + LM2 * sizeof(float);

    if (ws_size >= NEED) {
        float*    F     = (float*)(ws + F_OFF);
        ushort_t* Ht    = (ushort_t*)(ws + HT_OFF);
        ushort_t* Lt    = (ushort_t*)(ws + LT_OFF);
        float*    tbuf  = (float*)(ws + TB_OFF);
        float*    vbuf  = (float*)(ws + VB_OFF);
        float*    dpart = (float*)(ws + DP_OFF);
        float*    be    = (float*)(ws + BE_OFF);

        split_transpose<<<dim3(BDIM / 64, PDIM / 64), 256, 0, stream>>>(G, Ht, Lt);
        fisher_gemm_mfma<<<136, 512, 0, stream>>>(Ht, Lt, F);
        mirror_upper<<<120, 256, 0, stream>>>(F);

        for (int j = 0; j < LM2; ++j)
            lanczos_step<<<NB, 256, 0, stream>>>(F, vbuf, tbuf, dpart, be, j);
        lanczos_final2<<<1, 256, 0, stream>>>(dpart, be, (float*)d_out);
    } else {
        // fallback: round-1 path (needs only ~16.9 MB of ws)
        float* F  = (float*)d_ws;
        float* uA = F + (size_t)PDIM * PDIM;
        float* uB = uA + PDIM;
        float* t  = uB + PDIM;
        float* S  = t + PDIM;
        float* D  = S + (LMF + 2);

        fisher_gemm_fb<<<dim3(PDIM / BN, PDIM / BM), 256, 0, stream>>>(G, F);
        lanczos_init_fb<<<1, 256, 0, stream>>>(uA, uB, S, D);
        float* uc = uA;
        float* up = uB;
        for (int j = 0; j < LMF; ++j) {
            lanczos_mv_fb<<<PDIM / 4, 256, 0, stream>>>(F, uc, t, &D[j]);
            lanczos_upd_fb<<<PDIM / 256, 256, 0, stream>>>(t, uc, up, &S[j + 1], &S[j], &D[j], &S[j + 2]);
            float* tmp = up; up = uc; uc = tmp;
        }
        lanczos_final_fb<<<1, 1, 0, stream>>>(S, D, (float*)d_out);
    }
}